// Round 7
// baseline (903.326 us; speedup 1.0000x reference)
//
#include <hip/hip_runtime.h>
#include <cstdint>
#include <cstddef>

// ---------------------------------------------------------------------------
// Problem constants
// ---------------------------------------------------------------------------
#define B_SZ   2
#define T_SEQ  4096
#define DIM_   2048
#define NH_    16
#define HD_    128          // head dim
#define QKVD   (3*DIM_)     // 6144
#define SCALE_ 0.08838834764831845f   // 1/sqrt(128)
// SCALE_ * log2(e): folded into Q in rope_split so attn works in base-2 domain
#define QSCALE_ 0.12751879524343564f
#define TAU_    8.0f        // defer-max threshold (base-2); P bounded by 2^8

typedef __bf16 bf16x4 __attribute__((ext_vector_type(4)));
typedef __bf16 bf16x8 __attribute__((ext_vector_type(8)));
typedef float  f32x4  __attribute__((ext_vector_type(4)));

typedef const __attribute__((address_space(1))) void* gas_ptr_t;
typedef       __attribute__((address_space(3))) void* las_ptr_t;

#define GLOAD_LDS16(gp, lp) \
  __builtin_amdgcn_global_load_lds((gas_ptr_t)(gp), (las_ptr_t)(lp), 16, 0, 0)

#if defined(__has_builtin) && __has_builtin(__builtin_amdgcn_exp2f)
#define EXP2F(x) __builtin_amdgcn_exp2f(x)
#else
#define EXP2F(x) exp2f(x)
#endif

// ---------------------------------------------------------------------------
// fp32 -> bf16 cast
// ---------------------------------------------------------------------------
__global__ void cast_f32_bf16(const float* __restrict__ in,
                              __bf16* __restrict__ out, int n4) {
  int i = blockIdx.x * blockDim.x + threadIdx.x;
  if (i < n4) {
    float4 v = ((const float4*)in)[i];
    bf16x4 o = { (__bf16)v.x, (__bf16)v.y, (__bf16)v.z, (__bf16)v.w };
    ((bf16x4*)out)[i] = o;
  }
}

// ---------------------------------------------------------------------------
// bf16 GEMM (m97 pattern) — unchanged, known-good ~900 TF structure.
// ---------------------------------------------------------------------------
__device__ __forceinline__ void store_c(float* C, size_t idx, float v)  { C[idx] = v; }
__device__ __forceinline__ void store_c(__bf16* C, size_t idx, float v) { C[idx] = (__bf16)v; }

template <typename OutT>
__global__ __launch_bounds__(256, 2) void gemm_bt(const __bf16* __restrict__ A,
                                                  const __bf16* __restrict__ B,
                                                  OutT* __restrict__ C,
                                                  int M, int N, int K) {
  __shared__ __attribute__((aligned(16))) __bf16 As[128 * 32];
  __shared__ __attribute__((aligned(16))) __bf16 Bs[128 * 32];

  const int tid  = threadIdx.x;
  const int wave = tid >> 6;
  const int lane = tid & 63;
  const int lrow = lane & 15;
  const int quad = lane >> 4;
  const int m0 = blockIdx.x * 128;
  const int n0 = blockIdx.y * 128;
  const int wm = (wave & 1) * 64;
  const int wn = (wave >> 1) * 64;

  const __bf16* Ag = A + (size_t)(m0 + (tid >> 2)) * K + (tid & 3) * 8;
  const __bf16* Bg = B + (size_t)(n0 + (tid >> 2)) * K + (tid & 3) * 8;

  f32x4 acc[4][4] = {};

  for (int k0 = 0; k0 < K; k0 += 32) {
    __syncthreads();
    GLOAD_LDS16(Ag + k0,                 &As[wave * 16 * 32]);
    GLOAD_LDS16(Ag + k0 + (size_t)64*K,  &As[(64 + wave * 16) * 32]);
    GLOAD_LDS16(Bg + k0,                 &Bs[wave * 16 * 32]);
    GLOAD_LDS16(Bg + k0 + (size_t)64*K,  &Bs[(64 + wave * 16) * 32]);
    __syncthreads();

    bf16x8 a[4], b[4];
#pragma unroll
    for (int i = 0; i < 4; i++)
      a[i] = *(const bf16x8*)&As[(wm + i * 16 + lrow) * 32 + quad * 8];
#pragma unroll
    for (int j = 0; j < 4; j++)
      b[j] = *(const bf16x8*)&Bs[(wn + j * 16 + lrow) * 32 + quad * 8];
#pragma unroll
    for (int i = 0; i < 4; i++)
#pragma unroll
      for (int j = 0; j < 4; j++)
        acc[i][j] = __builtin_amdgcn_mfma_f32_16x16x32_bf16(a[i], b[j], acc[i][j], 0, 0, 0);
  }

#pragma unroll
  for (int i = 0; i < 4; i++)
#pragma unroll
    for (int j = 0; j < 4; j++)
#pragma unroll
      for (int r = 0; r < 4; r++) {
        size_t row = (size_t)(m0 + wm + i * 16 + quad * 4 + r);
        size_t col = (size_t)(n0 + wn + j * 16 + lrow);
        store_c(C, row * (size_t)N + col, acc[i][j][r]);
      }
}

// ---------------------------------------------------------------------------
// RoPE + split heads. Q,K: [bh][t][d] rope'd; Vt: [bh][d][t].
// Q is additionally scaled by SCALE*log2(e) so flash_attn softmax runs in
// base-2 domain with no per-element multiplies.
// ---------------------------------------------------------------------------
__global__ void rope_split(const __bf16* __restrict__ qkv,
                           __bf16* __restrict__ Qo,
                           __bf16* __restrict__ Ko,
                           __bf16* __restrict__ Vt) {
  const long id  = (long)blockIdx.x * blockDim.x + threadIdx.x;
  const int row = (int)(id / 3072);      // b*T + t
  const int p   = (int)(id % 3072);
  const int b = row >> 12;
  const int t = row & (T_SEQ - 1);
  const __bf16* src = qkv + (size_t)row * QKVD;

  if (p < 2048) {
    const bool isq = (p < 1024);
    const int pp = isq ? p : p - 1024;
    const int dp = pp * 2;
    const int h = dp >> 7, d = dp & 127;
    const int base = isq ? 0 : DIM_;
    const float x0 = (float)src[base + dp];
    const float x1 = (float)src[base + dp + 1];
    const int i0 = d & 63, i1 = (d + 1) & 63;
    const float kf = -0.20762050593049014f;   // -log2(10000)/64
    float a0 = (float)t * exp2f(i0 * kf);
    float a1 = (float)t * exp2f(i1 * kf);
    float s0, c0, s1, c1;
    sincosf(a0, &s0, &c0);
    sincosf(a1, &s1, &c1);
    float y0 = x0 * c0 - x1 * s0;
    float y1 = x1 * c1 + x0 * s1;
    if (isq) { y0 *= QSCALE_; y1 *= QSCALE_; }
    __bf16* dst = (isq ? Qo : Ko) + (((size_t)(b * NH_ + h) * T_SEQ + t) * HD_ + d);
    dst[0] = (__bf16)y0;
    dst[1] = (__bf16)y1;
  } else {
    const int dp = (p - 2048) * 2;
    const int h = dp >> 7, d = dp & 127;
    __bf16 v0 = src[2 * DIM_ + dp];
    __bf16 v1 = src[2 * DIM_ + dp + 1];
    size_t base = (size_t)(b * NH_ + h) * HD_;
    Vt[(base + d)     * T_SEQ + t] = v0;
    Vt[(base + d + 1) * T_SEQ + t] = v1;
  }
}

// ---------------------------------------------------------------------------
// Flash attention v10: 4 waves / 256 threads, 128 q-rows per block.
//
// R6 lesson: with 8-wave blocks, a second block needs 4 waves/SIMD, i.e.
// unified regs <= 128/thread — structurally unreachable (o+qf alone = 96;
// forcing it spilled in R5). With 4-wave blocks one block = 1 wave/SIMD,
// so TWO blocks need only 2 waves/SIMD (unified <= 256 — we're ~168-184).
// LDS = Ks 32K + Vs 32K + Ps[4] 8K = 72KB -> 2 blocks = 144KB < 160KB
// (slack; R0's exact 160 may also have blocked pairing). Two INDEPENDENT
// blocks/CU desync the phase lockstep: block B issues MFMA while block A
// drains staging at its barrier. Cost: K/V fetched 2x (irrelevant at 9%
// HBM). Geometry = R0-proven 4-wave form; softmax = R6-proven fused path.
// ---------------------------------------------------------------------------
__global__ __launch_bounds__(256, 2) void flash_attn(const __bf16* __restrict__ Q,
                                                     const __bf16* __restrict__ K,
                                                     const __bf16* __restrict__ Vt,
                                                     __bf16* __restrict__ O) {
  __shared__ __attribute__((aligned(16))) __bf16 Ks[2][64 * 128];   // 32 KB
  __shared__ __attribute__((aligned(16))) __bf16 Vs[2][128 * 64];   // 32 KB
  __shared__ __attribute__((aligned(16))) __bf16 Ps[4][16 * 64];    //  8 KB

  const int qb   = (gridDim.x - 1) - blockIdx.x;  // heavy blocks dispatch first
  const int bh   = blockIdx.y;
  const int tid  = threadIdx.x;
  const int wave = tid >> 6;                      // 0..3
  const int lane = tid & 63;
  const int l15  = lane & 15;
  const int quad = lane >> 4;

  const __bf16* Qh = Q  + (size_t)bh * T_SEQ * HD_;
  const __bf16* Kh = K  + (size_t)bh * T_SEQ * HD_;
  const __bf16* Vh = Vt + (size_t)bh * HD_ * T_SEQ;

  const int qw   = qb * 128 + wave * 32;   // wave's first q row
  const int kcnt = 2 * qb + 2;             // 64-key tiles

  // Q fragments (B-operand): 2 q-tiles x 4 d-chunks (32 VGPR)
  bf16x8 qf[2][4];
#pragma unroll
  for (int qt = 0; qt < 2; qt++)
#pragma unroll
    for (int kc = 0; kc < 4; kc++)
      qf[qt][kc] = *(const bf16x8*)&Qh[(size_t)(qw + qt * 16 + l15) * HD_ + kc * 32 + quad * 8];

  f32x4 o[2][8] = {};
  float m_[2] = {-1e30f, -1e30f};
  float l_[2] = {0.f, 0.f};

  // staging coords (256 thr): K 64 rows x 16 chunks (4 thr/row, 4 chunks ea);
  //                           V 128 rows x 8 chunks (2 thr/row, 4 chunks ea)
  const int krow = tid >> 2, kq4 = tid & 3;
  const int vrow = tid >> 1, vh2 = tid & 1;

  bf16x8 kpre[4], vpre[4];

#define LOAD_TILES(KB)                                                          \
  {                                                                             \
    const __bf16* kg = Kh + (size_t)((KB) * 64 + krow) * HD_;                   \
    const __bf16* vg = Vh + (size_t)vrow * T_SEQ + (KB) * 64;                   \
    _Pragma("unroll")                                                           \
    for (int j = 0; j < 4; j++) {                                               \
      kpre[j] = *(const bf16x8*)&kg[(j * 4 + kq4) * 8];                         \
      vpre[j] = *(const bf16x8*)&vg[(vh2 * 4 + j) * 8];                         \
    }                                                                           \
  }

#define STORE_TILES(BUF)                                                        \
  {                                                                             \
    _Pragma("unroll")                                                           \
    for (int j = 0; j < 4; j++) {                                               \
      int kc_ = (j * 4 + kq4) ^ (krow & 7);                                     \
      *(bf16x8*)&Ks[BUF][krow * 128 + kc_ * 8] = kpre[j];                       \
      int vc_ = (vh2 * 4 + j) ^ (vrow & 7);                                     \
      *(bf16x8*)&Vs[BUF][vrow * 64 + vc_ * 8] = vpre[j];                        \
    }                                                                           \
  }

  LOAD_TILES(0);
  STORE_TILES(0);
  if (kcnt > 1) LOAD_TILES(1);
  __syncthreads();

  for (int kb = 0; kb < kcnt; ++kb) {
    const int cur = kb & 1;
    // stage tile kb+1 into the other buffer (its last readers finished
    // at compute(kb-1), guarded by the barrier at the bottom of kb-1)
    if (kb + 1 < kcnt) STORE_TILES((kb + 1) & 1);
    if (kb + 2 < kcnt) LOAD_TILES(kb + 2);

    if (kb * 64 <= qw + 31) {   // wave has >=1 unmasked key this tile
      // ---- S^T = K Q^T : kf shared across both q-tiles ----
      f32x4 st[2][4];
#pragma unroll
      for (int kt = 0; kt < 4; kt++) {
        f32x4 a0 = {}, a1 = {};
        const int row = kt * 16 + l15;
#pragma unroll
        for (int kc = 0; kc < 4; kc++) {
          const int c = kc * 4 + quad;                 // chunk = (kc*32+quad*8)/8
          bf16x8 kf = *(const bf16x8*)&Ks[cur][row * 128 + (c ^ (row & 7)) * 8];
          a0 = __builtin_amdgcn_mfma_f32_16x16x32_bf16(kf, qf[0][kc], a0, 0, 0, 0);
          a1 = __builtin_amdgcn_mfma_f32_16x16x32_bf16(kf, qf[1][kc], a1, 0, 0, 0);
        }
        st[0][kt] = a0; st[1][kt] = a1;
      }

      // ---- causal mask (diagonal region only) ----
      if (kb * 64 + 63 > qw) {
#pragma unroll
        for (int qt = 0; qt < 2; qt++)
#pragma unroll
          for (int kt = 0; kt < 4; kt++)
#pragma unroll
            for (int r = 0; r < 4; r++) {
              int key = kb * 64 + kt * 16 + quad * 4 + r;
              int q   = qw + qt * 16 + l15;
              if (key > q) st[qt][kt][r] = -1e30f;
            }
      }

      // ---- per q-tile: softmax -> Ps write -> drain -> rescale -> PV ----
      // PV(qt=0)'s MFMAs issue before softmax(qt=1)'s VALU chain: the MFMA
      // pipe drains under the next tile's VALU work (intra-wave overlap).
#pragma unroll
      for (int qt = 0; qt < 2; qt++) {
        float mt = -1e30f;
#pragma unroll
        for (int kt = 0; kt < 4; kt++)
#pragma unroll
          for (int r = 0; r < 4; r++) mt = fmaxf(mt, st[qt][kt][r]);
        mt = fmaxf(mt, __shfl_xor(mt, 16));
        mt = fmaxf(mt, __shfl_xor(mt, 32));

        const bool need = __any(mt > m_[qt] + TAU_) != 0;   // wave-uniform
        float mnew, alpha;
        if (need) {
          mnew = fmaxf(m_[qt], mt);
          alpha = EXP2F(m_[qt] - mnew);
          m_[qt] = mnew;
        } else {
          mnew = m_[qt];
          alpha = 1.0f;
        }

        // exps into registers + row-sum
        float ps = 0.f;
        bf16x4 pk[4];
#pragma unroll
        for (int kt = 0; kt < 4; kt++)
#pragma unroll
          for (int r = 0; r < 4; r++) {
            float pv = EXP2F(st[qt][kt][r] - mnew);
            ps += pv;
            pk[kt][r] = (__bf16)pv;
          }
        ps += __shfl_xor(ps, 16);
        ps += __shfl_xor(ps, 32);
        l_[qt] = l_[qt] * alpha + ps;

        // Ps rows l15 are shared across qt: ensure the previous qt's pf
        // reads of these rows completed before overwriting (same-wave DS).
        __asm__ volatile("s_waitcnt lgkmcnt(0)" ::: "memory");
#pragma unroll
        for (int kt = 0; kt < 4; kt++) {
          const int ec = kt * 16 + quad * 4;           // element col in [0,64)
          const int c  = (ec >> 3) ^ (l15 & 7);        // swizzled 16B chunk
          *(bf16x4*)&Ps[wave][l15 * 64 + c * 8 + (ec & 7)] = pk[kt];
        }
        // per-wave LDS write->read ordering for Ps
        __asm__ volatile("s_waitcnt lgkmcnt(0)" ::: "memory");

        // rescale O (only when the running max actually moved)
        if (need) {
#pragma unroll
          for (int r = 0; r < 4; r++) {
            float a = __shfl(alpha, quad * 4 + r);
#pragma unroll
            for (int dt = 0; dt < 8; dt++) o[qt][dt][r] *= a;
          }
        }

        // O[qt] += P V
#pragma unroll
        for (int kc2 = 0; kc2 < 2; kc2++) {
          const int ec = kc2 * 32 + quad * 8;
          const int pc = (ec >> 3) ^ (l15 & 7);
          bf16x8 pf = *(const bf16x8*)&Ps[wave][l15 * 64 + pc * 8];
#pragma unroll
          for (int dt = 0; dt < 8; dt++) {
            const int vr = dt * 16 + l15;
            const int vc = (ec >> 3) ^ (vr & 7);
            bf16x8 vf = *(const bf16x8*)&Vs[cur][vr * 64 + vc * 8];
            o[qt][dt] = __builtin_amdgcn_mfma_f32_16x16x32_bf16(pf, vf, o[qt][dt], 0, 0, 0);
          }
        }
      }
    }
    __syncthreads();   // tile kb fully consumed; tile kb+1 writes visible
  }

  // ---- epilogue: O[b][t][h][d] = o / l ----
  const int b = bh >> 4, h = bh & 15;
#pragma unroll
  for (int qt = 0; qt < 2; qt++) {
    float il = 1.f / l_[qt];
#pragma unroll
    for (int r = 0; r < 4; r++) {
      float linv = __shfl(il, quad * 4 + r);
      int t = qw + qt * 16 + quad * 4 + r;
#pragma unroll
      for (int dt = 0; dt < 8; dt++) {
        size_t idx = (((size_t)b * T_SEQ + t) * NH_ + h) * HD_ + dt * 16 + l15;
        O[idx] = (__bf16)(o[qt][dt][r] * linv);
      }
    }
  }
}

// ---------------------------------------------------------------------------
// Launcher
// ---------------------------------------------------------------------------
extern "C" void kernel_launch(void* const* d_in, const int* in_sizes, int n_in,
                              void* d_out, int out_size, void* d_ws, size_t ws_size,
                              hipStream_t stream) {
  const float* x      = (const float*)d_in[0];
  const float* w_qkv  = (const float*)d_in[1];
  const float* w_proj = (const float*)d_in[2];
  float* out = (float*)d_out;

  char* ws = (char*)d_ws;
  const size_t SZ_X16   = (size_t)B_SZ * T_SEQ * DIM_ * 2;        // 33,554,432
  const size_t SZ_W16   = (size_t)QKVD * DIM_ * 2;                // 25,165,824
  const size_t SZ_WP16  = (size_t)DIM_ * DIM_ * 2;                //  8,388,608
  const size_t SZ_QKV16 = (size_t)B_SZ * T_SEQ * QKVD * 2;        // 100,663,296
  const size_t SZ_HEADS = SZ_X16;

  __bf16* x16   = (__bf16*)(ws);
  __bf16* w16   = (__bf16*)(ws + SZ_X16);
  __bf16* wp16  = (__bf16*)(ws + SZ_X16 + SZ_W16);
  __bf16* qkv16 = (__bf16*)(ws + SZ_X16 + SZ_W16 + SZ_WP16);
  __bf16* K16   = (__bf16*)(ws + SZ_X16 + SZ_W16 + SZ_WP16 + SZ_QKV16);
  __bf16* Vt16  = (__bf16*)(ws + SZ_X16 + SZ_W16 + SZ_WP16 + SZ_QKV16 + SZ_HEADS);
  __bf16* Q16   = x16;      // alias: x16 dead after QKV GEMM
  __bf16* O16   = qkv16;    // alias: qkv16 dead after rope_split

  const size_t NEED = SZ_X16 + SZ_W16 + SZ_WP16 + SZ_QKV16 + 2 * SZ_HEADS;
  if (ws_size < NEED) return;

  // 1) casts
  {
    int n4 = (int)((size_t)B_SZ * T_SEQ * DIM_ / 4);
    cast_f32_bf16<<<(n4 + 255) / 256, 256, 0, stream>>>(x, x16, n4);
    n4 = (int)((size_t)QKVD * DIM_ / 4);
    cast_f32_bf16<<<(n4 + 255) / 256, 256, 0, stream>>>(w_qkv, w16, n4);
    n4 = (int)((size_t)DIM_ * DIM_ / 4);
    cast_f32_bf16<<<(n4 + 255) / 256, 256, 0, stream>>>(w_proj, wp16, n4);
  }

  // 2) qkv = x @ w_qkv^T   [8192 x 6144]
  gemm_bt<__bf16><<<dim3(8192 / 128, QKVD / 128), 256, 0, stream>>>(
      x16, w16, qkv16, 8192, QKVD, DIM_);

  // 3) rope + head split (+ V transpose, + SCALE*log2e folded into Q)
  {
    long total = (long)B_SZ * T_SEQ * 3072;
    rope_split<<<(int)(total / 256), 256, 0, stream>>>(qkv16, Q16, K16, Vt16);
  }

  // 4) flash attention -> O16 [b][t][h][d]  (4 waves, 128 q-rows/block)
  flash_attn<<<dim3(T_SEQ / 128, B_SZ * NH_), 256, 0, stream>>>(Q16, K16, Vt16, O16);

  // 5) out = O @ w_proj^T  [8192 x 2048] fp32
  gemm_bt<float><<<dim3(8192 / 128, DIM_ / 128), 256, 0, stream>>>(
      O16, wp16, out, 8192, DIM_, DIM_);
}

// Round 8
// 867.498 us; speedup vs baseline: 1.0413x; 1.0413x over previous
//
#include <hip/hip_runtime.h>
#include <cstdint>
#include <cstddef>

// ---------------------------------------------------------------------------
// Problem constants
// ---------------------------------------------------------------------------
#define B_SZ   2
#define T_SEQ  4096
#define DIM_   2048
#define NH_    16
#define HD_    128          // head dim
#define QKVD   (3*DIM_)     // 6144
#define SCALE_ 0.08838834764831845f   // 1/sqrt(128)
// SCALE_ * log2(e): folded into Q in rope_split so attn works in base-2 domain
#define QSCALE_ 0.12751879524343564f
#define TAU_    8.0f        // defer-max threshold (base-2); P bounded by 2^8

typedef __bf16 bf16x4 __attribute__((ext_vector_type(4)));
typedef __bf16 bf16x8 __attribute__((ext_vector_type(8)));
typedef float  f32x4  __attribute__((ext_vector_type(4)));

typedef const __attribute__((address_space(1))) void* gas_ptr_t;
typedef       __attribute__((address_space(3))) void* las_ptr_t;

#define GLOAD_LDS16(gp, lp) \
  __builtin_amdgcn_global_load_lds((gas_ptr_t)(gp), (las_ptr_t)(lp), 16, 0, 0)

#if defined(__has_builtin) && __has_builtin(__builtin_amdgcn_exp2f)
#define EXP2F(x) __builtin_amdgcn_exp2f(x)
#else
#define EXP2F(x) exp2f(x)
#endif

// ---------------------------------------------------------------------------
// fp32 -> bf16 cast
// ---------------------------------------------------------------------------
__global__ void cast_f32_bf16(const float* __restrict__ in,
                              __bf16* __restrict__ out, int n4) {
  int i = blockIdx.x * blockDim.x + threadIdx.x;
  if (i < n4) {
    float4 v = ((const float4*)in)[i];
    bf16x4 o = { (__bf16)v.x, (__bf16)v.y, (__bf16)v.z, (__bf16)v.w };
    ((bf16x4*)out)[i] = o;
  }
}

// ---------------------------------------------------------------------------
// bf16 GEMM (m97 pattern) — unchanged, known-good ~900 TF structure.
// ---------------------------------------------------------------------------
__device__ __forceinline__ void store_c(float* C, size_t idx, float v)  { C[idx] = v; }
__device__ __forceinline__ void store_c(__bf16* C, size_t idx, float v) { C[idx] = (__bf16)v; }

template <typename OutT>
__global__ __launch_bounds__(256, 2) void gemm_bt(const __bf16* __restrict__ A,
                                                  const __bf16* __restrict__ B,
                                                  OutT* __restrict__ C,
                                                  int M, int N, int K) {
  __shared__ __attribute__((aligned(16))) __bf16 As[128 * 32];
  __shared__ __attribute__((aligned(16))) __bf16 Bs[128 * 32];

  const int tid  = threadIdx.x;
  const int wave = tid >> 6;
  const int lane = tid & 63;
  const int lrow = lane & 15;
  const int quad = lane >> 4;
  const int m0 = blockIdx.x * 128;
  const int n0 = blockIdx.y * 128;
  const int wm = (wave & 1) * 64;
  const int wn = (wave >> 1) * 64;

  const __bf16* Ag = A + (size_t)(m0 + (tid >> 2)) * K + (tid & 3) * 8;
  const __bf16* Bg = B + (size_t)(n0 + (tid >> 2)) * K + (tid & 3) * 8;

  f32x4 acc[4][4] = {};

  for (int k0 = 0; k0 < K; k0 += 32) {
    __syncthreads();
    GLOAD_LDS16(Ag + k0,                 &As[wave * 16 * 32]);
    GLOAD_LDS16(Ag + k0 + (size_t)64*K,  &As[(64 + wave * 16) * 32]);
    GLOAD_LDS16(Bg + k0,                 &Bs[wave * 16 * 32]);
    GLOAD_LDS16(Bg + k0 + (size_t)64*K,  &Bs[(64 + wave * 16) * 32]);
    __syncthreads();

    bf16x8 a[4], b[4];
#pragma unroll
    for (int i = 0; i < 4; i++)
      a[i] = *(const bf16x8*)&As[(wm + i * 16 + lrow) * 32 + quad * 8];
#pragma unroll
    for (int j = 0; j < 4; j++)
      b[j] = *(const bf16x8*)&Bs[(wn + j * 16 + lrow) * 32 + quad * 8];
#pragma unroll
    for (int i = 0; i < 4; i++)
#pragma unroll
      for (int j = 0; j < 4; j++)
        acc[i][j] = __builtin_amdgcn_mfma_f32_16x16x32_bf16(a[i], b[j], acc[i][j], 0, 0, 0);
  }

#pragma unroll
  for (int i = 0; i < 4; i++)
#pragma unroll
    for (int j = 0; j < 4; j++)
#pragma unroll
      for (int r = 0; r < 4; r++) {
        size_t row = (size_t)(m0 + wm + i * 16 + quad * 4 + r);
        size_t col = (size_t)(n0 + wn + j * 16 + lrow);
        store_c(C, row * (size_t)N + col, acc[i][j][r]);
      }
}

// ---------------------------------------------------------------------------
// RoPE + split heads. Q,K: [bh][t][d] rope'd; Vt: [bh][d][t].
// Q is additionally scaled by SCALE*log2(e) so flash_attn softmax runs in
// base-2 domain with no per-element multiplies.
// ---------------------------------------------------------------------------
__global__ void rope_split(const __bf16* __restrict__ qkv,
                           __bf16* __restrict__ Qo,
                           __bf16* __restrict__ Ko,
                           __bf16* __restrict__ Vt) {
  const long id  = (long)blockIdx.x * blockDim.x + threadIdx.x;
  const int row = (int)(id / 3072);      // b*T + t
  const int p   = (int)(id % 3072);
  const int b = row >> 12;
  const int t = row & (T_SEQ - 1);
  const __bf16* src = qkv + (size_t)row * QKVD;

  if (p < 2048) {
    const bool isq = (p < 1024);
    const int pp = isq ? p : p - 1024;
    const int dp = pp * 2;
    const int h = dp >> 7, d = dp & 127;
    const int base = isq ? 0 : DIM_;
    const float x0 = (float)src[base + dp];
    const float x1 = (float)src[base + dp + 1];
    const int i0 = d & 63, i1 = (d + 1) & 63;
    const float kf = -0.20762050593049014f;   // -log2(10000)/64
    float a0 = (float)t * exp2f(i0 * kf);
    float a1 = (float)t * exp2f(i1 * kf);
    float s0, c0, s1, c1;
    sincosf(a0, &s0, &c0);
    sincosf(a1, &s1, &c1);
    float y0 = x0 * c0 - x1 * s0;
    float y1 = x1 * c1 + x0 * s1;
    if (isq) { y0 *= QSCALE_; y1 *= QSCALE_; }
    __bf16* dst = (isq ? Qo : Ko) + (((size_t)(b * NH_ + h) * T_SEQ + t) * HD_ + d);
    dst[0] = (__bf16)y0;
    dst[1] = (__bf16)y1;
  } else {
    const int dp = (p - 2048) * 2;
    const int h = dp >> 7, d = dp & 127;
    __bf16 v0 = src[2 * DIM_ + dp];
    __bf16 v1 = src[2 * DIM_ + dp + 1];
    size_t base = (size_t)(b * NH_ + h) * HD_;
    Vt[(base + d)     * T_SEQ + t] = v0;
    Vt[(base + d + 1) * T_SEQ + t] = v1;
  }
}

// ---------------------------------------------------------------------------
// Flash attention v11 = R4-proven kernel (8 waves, batched softmax, shared-vf
// PV, base-2 + defer-max) with ONE change: K/V staging via global_load_lds
// with PRE-SWIZZLED global source (m173/m97 pattern, same builtin our GEMM
// uses in this file).
//
// Theory (R7 post-mortem): kernel is LDS-THROUGHPUT-bound (~500 wave-wide
// LDS ops/CU/tile saturate the shared LDS pipe; explains why occupancy
// changes R1/R6/R7 were all null). DMA staging removes the 4 ds_write_b128
// per wave per tile from the wave-issued stream, frees kpre/vpre (16 VGPR)
// and staging-address VALU. Involution: LDS[row][c] = global[row][c^(row&7)],
// linear LDS dest (base + lane*16), read side UNCHANGED. Row parity is
// preserved across the +32/+64-row halves since (r+32)&7 == r&7.
// Single-variable change vs R4 => clean attribution (staging was never
// convicted: R3's bisect convicted only the shuffle network).
// ---------------------------------------------------------------------------
__global__ __launch_bounds__(512, 2) void flash_attn(const __bf16* __restrict__ Q,
                                                     const __bf16* __restrict__ K,
                                                     const __bf16* __restrict__ Vt,
                                                     __bf16* __restrict__ O) {
  __shared__ __attribute__((aligned(16))) __bf16 Ks[2][64 * 128];   // 32 KB
  __shared__ __attribute__((aligned(16))) __bf16 Vs[2][128 * 64];   // 32 KB
  __shared__ __attribute__((aligned(16))) __bf16 Ps[8][32 * 64];    // 32 KB

  const int qb   = (gridDim.x - 1) - blockIdx.x;  // heavy blocks dispatch first
  const int bh   = blockIdx.y;
  const int tid  = threadIdx.x;
  const int wave = tid >> 6;                      // 0..7
  const int lane = tid & 63;
  const int l15  = lane & 15;
  const int quad = lane >> 4;

  const __bf16* Qh = Q  + (size_t)bh * T_SEQ * HD_;
  const __bf16* Kh = K  + (size_t)bh * T_SEQ * HD_;
  const __bf16* Vh = Vt + (size_t)bh * HD_ * T_SEQ;

  const int qw   = qb * 256 + wave * 32;   // wave's first q row
  const int kcnt = 4 * qb + 4;             // 64-key tiles

  // Q fragments (B-operand): 2 q-tiles x 4 d-chunks (32 VGPR)
  bf16x8 qf[2][4];
#pragma unroll
  for (int qt = 0; qt < 2; qt++)
#pragma unroll
    for (int kc = 0; kc < 4; kc++)
      qf[qt][kc] = *(const bf16x8*)&Qh[(size_t)(qw + qt * 16 + l15) * HD_ + kc * 32 + quad * 8];

  f32x4 o[2][8] = {};
  float m_[2] = {-1e30f, -1e30f};
  float l_[2] = {0.f, 0.f};

  // ---- global_load_lds staging geometry (pre-swizzled global source) ----
  // K: 64 rows x 16 chunks of 16B. Each wave DMAs rows wave*4..wave*4+3
  //    (and +32): lane -> row wave*4 + (lane>>4), LDS chunk lane&15,
  //    source chunk (lane&15) ^ (row&7).
  // V: 128 rows x 8 chunks of 16B. Each wave DMAs rows wave*8..wave*8+7
  //    (and +64): lane -> row wave*8 + (lane>>3), LDS chunk lane&7,
  //    source chunk (lane&7) ^ (row&7).
  const int kRow = wave * 4 + (lane >> 4);
  const size_t kSrc = (size_t)kRow * HD_ + (size_t)(((lane & 15) ^ (kRow & 7)) * 8);
  const int vRow = wave * 8 + (lane >> 3);
  const size_t vSrc = (size_t)vRow * T_SEQ + (size_t)(((lane & 7) ^ (vRow & 7)) * 8);

#define STAGE(BUF, KB)                                                          \
  {                                                                             \
    const __bf16* kg = Kh + (size_t)(KB) * (64 * HD_) + kSrc;                   \
    const __bf16* vg = Vh + (size_t)(KB) * 64 + vSrc;                           \
    GLOAD_LDS16(kg,                 &Ks[BUF][wave * 512]);                      \
    GLOAD_LDS16(kg + 32 * HD_,      &Ks[BUF][32 * 128 + wave * 512]);           \
    GLOAD_LDS16(vg,                 &Vs[BUF][wave * 512]);                      \
    GLOAD_LDS16(vg + 64 * T_SEQ,    &Vs[BUF][64 * 64 + wave * 512]);            \
  }

  STAGE(0, 0);
  __syncthreads();   // vmcnt(0)+barrier: tile 0 resident

  for (int kb = 0; kb < kcnt; ++kb) {
    const int cur = kb & 1;
    // DMA tile kb+1 into the other buffer. Its last readers finished at
    // compute(kb-1), before the barrier that ended iter kb-1. These loads
    // drain at this iteration's closing barrier (vmcnt(0) before s_barrier).
    if (kb + 1 < kcnt) STAGE((kb + 1) & 1, kb + 1);

    if (kb * 64 <= qw + 31) {   // wave has >=1 unmasked key this tile
      // ---- S^T = K Q^T : kf shared across both q-tiles ----
      f32x4 st[2][4];
#pragma unroll
      for (int kt = 0; kt < 4; kt++) {
        f32x4 a0 = {}, a1 = {};
        const int row = kt * 16 + l15;
#pragma unroll
        for (int kc = 0; kc < 4; kc++) {
          const int c = kc * 4 + quad;                 // chunk = (kc*32+quad*8)/8
          bf16x8 kf = *(const bf16x8*)&Ks[cur][row * 128 + (c ^ (row & 7)) * 8];
          a0 = __builtin_amdgcn_mfma_f32_16x16x32_bf16(kf, qf[0][kc], a0, 0, 0, 0);
          a1 = __builtin_amdgcn_mfma_f32_16x16x32_bf16(kf, qf[1][kc], a1, 0, 0, 0);
        }
        st[0][kt] = a0; st[1][kt] = a1;
      }

      // ---- causal mask (diagonal region only) ----
      if (kb * 64 + 63 > qw) {
#pragma unroll
        for (int qt = 0; qt < 2; qt++)
#pragma unroll
          for (int kt = 0; kt < 4; kt++)
#pragma unroll
            for (int r = 0; r < 4; r++) {
              int key = kb * 64 + kt * 16 + quad * 4 + r;
              int q   = qw + qt * 16 + l15;
              if (key > q) st[qt][kt][r] = -1e30f;
            }
      }

      // ---- online softmax (base-2, defer-max) + P write (per q-tile) ----
      float alpha[2];
      bool  needr[2];
#pragma unroll
      for (int qt = 0; qt < 2; qt++) {
        float mt = -1e30f;
#pragma unroll
        for (int kt = 0; kt < 4; kt++)
#pragma unroll
          for (int r = 0; r < 4; r++) mt = fmaxf(mt, st[qt][kt][r]);
        mt = fmaxf(mt, __shfl_xor(mt, 16));
        mt = fmaxf(mt, __shfl_xor(mt, 32));

        const bool need = __any(mt > m_[qt] + TAU_) != 0;   // wave-uniform
        needr[qt] = need;
        float mnew;
        if (need) {
          mnew = fmaxf(m_[qt], mt);
          alpha[qt] = EXP2F(m_[qt] - mnew);
          m_[qt] = mnew;
        } else {
          mnew = m_[qt];
          alpha[qt] = 1.0f;
        }

        float ps = 0.f;
        const int prow = qt * 16 + l15;
#pragma unroll
        for (int kt = 0; kt < 4; kt++) {
          bf16x4 pk;
#pragma unroll
          for (int r = 0; r < 4; r++) {
            float pv = EXP2F(st[qt][kt][r] - mnew);
            ps += pv;
            pk[r] = (__bf16)pv;
          }
          const int ec = kt * 16 + quad * 4;           // element col in [0,64)
          const int c  = (ec >> 3) ^ (prow & 7);       // swizzled 16B chunk
          *(bf16x4*)&Ps[wave][prow * 64 + c * 8 + (ec & 7)] = pk;
        }
        ps += __shfl_xor(ps, 16);
        ps += __shfl_xor(ps, 32);
        l_[qt] = l_[qt] * alpha[qt] + ps;
      }

      // per-wave LDS write->read ordering for Ps
      __asm__ volatile("s_waitcnt lgkmcnt(0)" ::: "memory");

      // ---- rescale O (only when the running max actually moved) ----
#pragma unroll
      for (int qt = 0; qt < 2; qt++)
        if (needr[qt]) {
#pragma unroll
          for (int r = 0; r < 4; r++) {
            float a = __shfl(alpha[qt], quad * 4 + r);
#pragma unroll
            for (int dt = 0; dt < 8; dt++) o[qt][dt][r] *= a;
          }
        }

      // ---- O += P V : vf shared across both q-tiles ----
#pragma unroll
      for (int kc2 = 0; kc2 < 2; kc2++) {
        const int ec = kc2 * 32 + quad * 8;
        const int pc = (ec >> 3) ^ (l15 & 7);          // (qt*16+l15)&7 == l15&7
        bf16x8 pf0 = *(const bf16x8*)&Ps[wave][(l15)      * 64 + pc * 8];
        bf16x8 pf1 = *(const bf16x8*)&Ps[wave][(16 + l15) * 64 + pc * 8];
#pragma unroll
        for (int dt = 0; dt < 8; dt++) {
          const int vr = dt * 16 + l15;
          const int vc = (ec >> 3) ^ (vr & 7);
          bf16x8 vf = *(const bf16x8*)&Vs[cur][vr * 64 + vc * 8];
          o[0][dt] = __builtin_amdgcn_mfma_f32_16x16x32_bf16(pf0, vf, o[0][dt], 0, 0, 0);
          o[1][dt] = __builtin_amdgcn_mfma_f32_16x16x32_bf16(pf1, vf, o[1][dt], 0, 0, 0);
        }
      }
    }
    __syncthreads();   // tile kb consumed; tile kb+1 DMA drained + visible
  }

  // ---- epilogue: O[b][t][h][d] = o / l ----
  const int b = bh >> 4, h = bh & 15;
#pragma unroll
  for (int qt = 0; qt < 2; qt++) {
    float il = 1.f / l_[qt];
#pragma unroll
    for (int r = 0; r < 4; r++) {
      float linv = __shfl(il, quad * 4 + r);
      int t = qw + qt * 16 + quad * 4 + r;
#pragma unroll
      for (int dt = 0; dt < 8; dt++) {
        size_t idx = (((size_t)b * T_SEQ + t) * NH_ + h) * HD_ + dt * 16 + l15;
        O[idx] = (__bf16)(o[qt][dt][r] * linv);
      }
    }
  }
}

// ---------------------------------------------------------------------------
// Launcher
// ---------------------------------------------------------------------------
extern "C" void kernel_launch(void* const* d_in, const int* in_sizes, int n_in,
                              void* d_out, int out_size, void* d_ws, size_t ws_size,
                              hipStream_t stream) {
  const float* x      = (const float*)d_in[0];
  const float* w_qkv  = (const float*)d_in[1];
  const float* w_proj = (const float*)d_in[2];
  float* out = (float*)d_out;

  char* ws = (char*)d_ws;
  const size_t SZ_X16   = (size_t)B_SZ * T_SEQ * DIM_ * 2;        // 33,554,432
  const size_t SZ_W16   = (size_t)QKVD * DIM_ * 2;                // 25,165,824
  const size_t SZ_WP16  = (size_t)DIM_ * DIM_ * 2;                //  8,388,608
  const size_t SZ_QKV16 = (size_t)B_SZ * T_SEQ * QKVD * 2;        // 100,663,296
  const size_t SZ_HEADS = SZ_X16;

  __bf16* x16   = (__bf16*)(ws);
  __bf16* w16   = (__bf16*)(ws + SZ_X16);
  __bf16* wp16  = (__bf16*)(ws + SZ_X16 + SZ_W16);
  __bf16* qkv16 = (__bf16*)(ws + SZ_X16 + SZ_W16 + SZ_WP16);
  __bf16* K16   = (__bf16*)(ws + SZ_X16 + SZ_W16 + SZ_WP16 + SZ_QKV16);
  __bf16* Vt16  = (__bf16*)(ws + SZ_X16 + SZ_W16 + SZ_WP16 + SZ_QKV16 + SZ_HEADS);
  __bf16* Q16   = x16;      // alias: x16 dead after QKV GEMM
  __bf16* O16   = qkv16;    // alias: qkv16 dead after rope_split

  const size_t NEED = SZ_X16 + SZ_W16 + SZ_WP16 + SZ_QKV16 + 2 * SZ_HEADS;
  if (ws_size < NEED) return;

  // 1) casts
  {
    int n4 = (int)((size_t)B_SZ * T_SEQ * DIM_ / 4);
    cast_f32_bf16<<<(n4 + 255) / 256, 256, 0, stream>>>(x, x16, n4);
    n4 = (int)((size_t)QKVD * DIM_ / 4);
    cast_f32_bf16<<<(n4 + 255) / 256, 256, 0, stream>>>(w_qkv, w16, n4);
    n4 = (int)((size_t)DIM_ * DIM_ / 4);
    cast_f32_bf16<<<(n4 + 255) / 256, 256, 0, stream>>>(w_proj, wp16, n4);
  }

  // 2) qkv = x @ w_qkv^T   [8192 x 6144]
  gemm_bt<__bf16><<<dim3(8192 / 128, QKVD / 128), 256, 0, stream>>>(
      x16, w16, qkv16, 8192, QKVD, DIM_);

  // 3) rope + head split (+ V transpose, + SCALE*log2e folded into Q)
  {
    long total = (long)B_SZ * T_SEQ * 3072;
    rope_split<<<(int)(total / 256), 256, 0, stream>>>(qkv16, Q16, K16, Vt16);
  }

  // 4) flash attention -> O16 [b][t][h][d]  (8 waves, 256 q-rows/block)
  flash_attn<<<dim3(T_SEQ / 256, B_SZ * NH_), 512, 0, stream>>>(Q16, K16, Vt16, O16);

  // 5) out = O @ w_proj^T  [8192 x 2048] fp32
  gemm_bt<float><<<dim3(8192 / 128, DIM_ / 128), 256, 0, stream>>>(
      O16, wp16, out, 8192, DIM_, DIM_);
}